// Round 3
// baseline (495.358 us; speedup 1.0000x reference)
//
#include <hip/hip_runtime.h>
#include <hip/hip_bf16.h>
#include <math.h>

typedef __bf16 bf16x8 __attribute__((ext_vector_type(8)));
typedef __bf16 bf16x4 __attribute__((ext_vector_type(4)));
typedef float  f32x4  __attribute__((ext_vector_type(4)));

#define DEV static __device__ __forceinline__

DEV unsigned short f2bf(float f) {
    unsigned u = __builtin_bit_cast(unsigned, f);
    u += 0x7fffu + ((u >> 16) & 1u);     // RNE
    return (unsigned short)(u >> 16);
}
DEV float bf2f(unsigned short u) {
    unsigned x = ((unsigned)u) << 16;
    return __builtin_bit_cast(float, x);
}

// ---------------- fp32 -> bf16 weight convert ----------------
__global__ void k_cvt(const float* __restrict__ in, unsigned short* __restrict__ out) {
    int i = (blockIdx.x * 256 + threadIdx.x) * 4;
    float4 v = *(const float4*)(in + i);
    ushort4 o;
    o.x = f2bf(v.x); o.y = f2bf(v.y); o.z = f2bf(v.z); o.w = f2bf(v.w);
    *(ushort4*)(out + i) = o;
}

// ---------------- adaLN: ada = silu(c) @ Wada^T + bada ----------------
__global__ void k_ada(const float* __restrict__ c, const float* __restrict__ Wada,
                      const float* __restrict__ bada, float* __restrict__ ada) {
    __shared__ float sc[1024];
    int b = blockIdx.x;
    int tid = threadIdx.x;
    for (int k = tid; k < 1024; k += 256) {
        float x = c[b * 1024 + k];
        sc[k] = x / (1.f + __expf(-x));
    }
    __syncthreads();
    int wid = tid >> 6, lane = tid & 63;
    int n = blockIdx.y * 4 + wid;
    const float* wr = Wada + (size_t)n * 1024;
    float acc = 0.f;
    #pragma unroll
    for (int k = 0; k < 1024; k += 64) acc += sc[k + lane] * wr[k + lane];
    #pragma unroll
    for (int o = 32; o; o >>= 1) acc += __shfl_xor(acc, o);
    if (lane == 0) ada[b * 6144 + n] = acc + bada[n];
}

// ---------------- fused rmsnorm + modulate -> bf16 ----------------
__global__ void k_norm_mod(const float* __restrict__ x, const float* __restrict__ ada,
                           const float* __restrict__ g, unsigned short* __restrict__ h,
                           int shift_off, int scale_off) {
    int row = blockIdx.x;
    int b = row >> 10;
    int tid = threadIdx.x;
    float4 v = *(const float4*)(x + (size_t)row * 1024 + tid * 4);
    float ss = v.x * v.x + v.y * v.y + v.z * v.z + v.w * v.w;
    #pragma unroll
    for (int o = 32; o; o >>= 1) ss += __shfl_xor(ss, o);
    __shared__ float red[4];
    int wid = tid >> 6, lane = tid & 63;
    if (lane == 0) red[wid] = ss;
    __syncthreads();
    float nrm = sqrtf(red[0] + red[1] + red[2] + red[3]);
    float f = g[0] * 32.f / fmaxf(nrm, 1e-12f);
    float4 s4 = *(const float4*)(ada + b * 6144 + scale_off + tid * 4);
    float4 h4 = *(const float4*)(ada + b * 6144 + shift_off + tid * 4);
    ushort4 o;
    o.x = f2bf(v.x * f * (1.f + s4.x) + h4.x);
    o.y = f2bf(v.y * f * (1.f + s4.y) + h4.y);
    o.z = f2bf(v.z * f * (1.f + s4.z) + h4.z);
    o.w = f2bf(v.w * f * (1.f + s4.w) + h4.w);
    *(ushort4*)(h + (size_t)row * 1024 + tid * 4) = o;
}

// ============ pipelined bf16 GEMM: C[m,n] = sum_k A[m,k]*B[n,k] (+epilogue) ============
// BM=256, BN=256/128, BK=32, 512 threads (8 waves), 4-slot LDS ring, stage depth 3,
// counted vmcnt (never 0 in steady state), XOR-swizzled LDS, setprio MFMA clusters.
// EPI: 0 = +bias -> bf16 | 1 = resid+gate*(+bias) -> f32 | 2 = gelu(+bias) -> bf16
//      3 = resid+gate*(+bias) -> f32
template <int EPI, int BN>
__global__ __launch_bounds__(512, 2)
void k_gemm2(const unsigned short* __restrict__ A, const unsigned short* __restrict__ Bw,
             const float* __restrict__ bias, int N, int K, int gridM,
             float* __restrict__ outF, unsigned short* __restrict__ outH,
             const float* __restrict__ resid, const float* __restrict__ ada, int gate_off) {
    constexpr int WN = (BN == 256) ? 4 : 2;     // waves along N
    constexpr int WM = 8 / WN;                  // waves along M
    constexpr int WR = 256 / WM;                // rows per wave (128 / 64)
    constexpr int MF = WR / 16;                 // m-frags per wave (8 / 4)
    constexpr int MF2 = MF / 2;
    constexpr int LB = BN / 128;                // B loads/thread/tile (2 / 1)
    constexpr int TL = 2 + LB;                  // loads/wave/tile
    __shared__ unsigned short sA[4][256 * 32];
    __shared__ unsigned short sB[4][BN * 32];

    int tid = threadIdx.x;
    int wid = tid >> 6, lane = tid & 63;
    int li = lane & 15, lg = lane >> 4;

    // XCD-aware block swizzle (grid % 8 == 0 for all call sites)
    int nwg = gridDim.x;
    int cpx = nwg >> 3;
    int bid = blockIdx.x;
    int v = (bid & 7) * cpx + (bid >> 3);
    int mb = v % gridM, nb = v / gridM;
    int m0 = mb * 256, n0 = nb * BN;

    int wr = (wid / WN) * WR, wc = (wid % WN) * 64;

    // stage-side swizzle: granule g of row r sources global granule g ^ f(r)
    int arow = tid >> 2, ag = tid & 3;
    int afr = (arow & 3) ^ ((arow >> 2) & 3);
    int ags = (ag ^ afr) * 8;                   // element offset within 32-elem K slice
    // read-side: row & 15 == li for all fragment rows
    int lfr = (li & 3) ^ ((li >> 2) & 3);
    int aoff = li * 32 + ((lg ^ lfr) * 8);      // element offset within a tile row block

    auto stageA = [&](int t) {
        int slot = t & 3;
        int kk = t << 5;
        #pragma unroll
        for (int l = 0; l < 2; ++l) {
            int row = arow + l * 128;
            const unsigned short* src = A + (size_t)(m0 + row) * K + kk + ags;
            unsigned short* dst = &sA[slot][0] + (l * 512 + wid * 64) * 8;  // wave-uniform
            __builtin_amdgcn_global_load_lds((const __attribute__((address_space(1))) void*)src,
                                             (__attribute__((address_space(3))) void*)dst, 16, 0, 0);
        }
    };
    auto stageB = [&](int t) {
        int slot = t & 3;
        int kk = t << 5;
        #pragma unroll
        for (int l = 0; l < LB; ++l) {
            int row = arow + l * 128;
            const unsigned short* src = Bw + (size_t)(n0 + row) * K + kk + ags;
            unsigned short* dst = &sB[slot][0] + (l * 512 + wid * 64) * 8;
            __builtin_amdgcn_global_load_lds((const __attribute__((address_space(1))) void*)src,
                                             (__attribute__((address_space(3))) void*)dst, 16, 0, 0);
        }
    };

    int NT = K >> 5;
    // prologue: stage tiles 0,1,2; wait tile 0 landed (2 tiles may stay in flight)
    stageA(0); stageB(0); stageA(1); stageB(1); stageA(2); stageB(2);
    asm volatile("s_waitcnt vmcnt(%0)" :: "n"(2 * TL) : "memory");
    __builtin_amdgcn_s_barrier();

    f32x4 acc[MF][4] = {};

    for (int t = 0; t < NT; ++t) {
        int slot = t & 3;
        const unsigned short* pa = &sA[slot][0];
        const unsigned short* pb = &sB[slot][0];
        bf16x8 bfr[4];
        bf16x8 af[MF2];
        // ---- phase 0: stage A(t+3) | read B-frags + A-half 0 | 16(8) MFMA ----
        if (t + 3 < NT) stageA(t + 3);
        #pragma unroll
        for (int nf = 0; nf < 4; ++nf)
            bfr[nf] = *(const bf16x8*)(pb + (wc + nf * 16) * 32 + aoff);
        #pragma unroll
        for (int m = 0; m < MF2; ++m)
            af[m] = *(const bf16x8*)(pa + (wr + m * 16) * 32 + aoff);
        __builtin_amdgcn_s_barrier();
        __builtin_amdgcn_s_setprio(1);
        #pragma unroll
        for (int m = 0; m < MF2; ++m)
            #pragma unroll
            for (int nf = 0; nf < 4; ++nf)
                acc[m][nf] = __builtin_amdgcn_mfma_f32_16x16x32_bf16(af[m], bfr[nf], acc[m][nf], 0, 0, 0);
        __builtin_amdgcn_s_setprio(0);
        // ---- phase 1: stage B(t+3) | read A-half 1 | 16(8) MFMA ----
        if (t + 3 < NT) stageB(t + 3);
        #pragma unroll
        for (int m = 0; m < MF2; ++m)
            af[m] = *(const bf16x8*)(pa + (wr + (MF2 + m) * 16) * 32 + aoff);
        __builtin_amdgcn_s_barrier();
        __builtin_amdgcn_s_setprio(1);
        #pragma unroll
        for (int m = 0; m < MF2; ++m)
            #pragma unroll
            for (int nf = 0; nf < 4; ++nf)
                acc[MF2 + m][nf] = __builtin_amdgcn_mfma_f32_16x16x32_bf16(af[m], bfr[nf], acc[MF2 + m][nf], 0, 0, 0);
        __builtin_amdgcn_s_setprio(0);
        // ---- tile end: counted vmcnt so tile t+1 is landed; never 0 until tail ----
        if (t < NT - 3)       asm volatile("s_waitcnt vmcnt(%0)" :: "n"(2 * TL) : "memory");
        else if (t == NT - 3) asm volatile("s_waitcnt vmcnt(%0)" :: "n"(TL) : "memory");
        else if (t == NT - 2) asm volatile("s_waitcnt vmcnt(0)" ::: "memory");
        __builtin_amdgcn_s_barrier();
    }

    // epilogue
    int rb4 = lg * 4;
    #pragma unroll
    for (int mf = 0; mf < MF; ++mf) {
        #pragma unroll
        for (int nf = 0; nf < 4; ++nf) {
            #pragma unroll
            for (int r = 0; r < 4; ++r) {
                int row = m0 + wr + mf * 16 + rb4 + r;
                int col = n0 + wc + nf * 16 + li;
                float vv = acc[mf][nf][r] + bias[col];
                if (EPI == 0) {
                    outH[(size_t)row * N + col] = f2bf(vv);
                } else if (EPI == 2) {
                    float a2 = 0.7978845608f * (vv + 0.044715f * vv * vv * vv);
                    float e = __expf(-2.f * fabsf(a2));
                    float th = copysignf((1.f - e) / (1.f + e), a2);
                    outH[(size_t)row * N + col] = f2bf(0.5f * vv * (1.f + th));
                } else {
                    int b = row >> 10;
                    float gt = ada[b * 6144 + gate_off + col];
                    outF[(size_t)row * N + col] = resid[(size_t)row * N + col] + gt * vv;
                }
            }
        }
    }
}

// ---------------- qkv post: q/k rms-norm -> Qb/Kb bf16; V -> Vt [B,H,64,T] ----------------
__global__ __launch_bounds__(256)
void k_qkv_post(const unsigned short* __restrict__ qkv,   // [8192][3072] bf16
                const float* __restrict__ gq, const float* __restrict__ gk,
                unsigned short* __restrict__ Qb, unsigned short* __restrict__ Kb,
                unsigned short* __restrict__ Vtg) {
    __shared__ unsigned short vt[64 * 72];
    int bh = blockIdx.x;
    int b = bh >> 4, h = bh & 15;
    int t0 = blockIdx.y * 64;
    int tid = threadIdx.x;
    int row = tid >> 2, part = tid & 3;
    size_t rbase = ((size_t)(b * 1024 + t0 + row)) * 3072 + h * 64 + part * 16;
    size_t obase = (size_t)bh * 65536 + (size_t)(t0 + row) * 64 + part * 16;

    #pragma unroll
    for (int s = 0; s < 2; ++s) {   // 0 = q, 1 = k
        uint4 u0 = *(const uint4*)(qkv + rbase + s * 1024);
        uint4 u1 = *(const uint4*)(qkv + rbase + s * 1024 + 8);
        float vals[16];
        const unsigned* pu = (const unsigned*)&u0;
        #pragma unroll
        for (int j = 0; j < 4; ++j) {
            vals[2*j]   = bf2f((unsigned short)(pu[j] & 0xffff));
            vals[2*j+1] = bf2f((unsigned short)(pu[j] >> 16));
        }
        pu = (const unsigned*)&u1;
        #pragma unroll
        for (int j = 0; j < 4; ++j) {
            vals[8+2*j]   = bf2f((unsigned short)(pu[j] & 0xffff));
            vals[8+2*j+1] = bf2f((unsigned short)(pu[j] >> 16));
        }
        float ss = 0.f;
        #pragma unroll
        for (int j = 0; j < 16; ++j) ss += vals[j] * vals[j];
        ss += __shfl_xor(ss, 1);
        ss += __shfl_xor(ss, 2);
        float nrm = fmaxf(sqrtf(ss), 1e-12f);
        float fsc = (s == 0 ? gq[0] : 8.f * gk[0]) / nrm;
        uint4 w0, w1;
        unsigned* pw = (unsigned*)&w0;
        #pragma unroll
        for (int j = 0; j < 4; ++j)
            pw[j] = (unsigned)f2bf(vals[2*j] * fsc) | ((unsigned)f2bf(vals[2*j+1] * fsc) << 16);
        pw = (unsigned*)&w1;
        #pragma unroll
        for (int j = 0; j < 4; ++j)
            pw[j] = (unsigned)f2bf(vals[8+2*j] * fsc) | ((unsigned)f2bf(vals[8+2*j+1] * fsc) << 16);
        unsigned short* dst = (s == 0 ? Qb : Kb);
        *(uint4*)(dst + obase)     = w0;
        *(uint4*)(dst + obase + 8) = w1;
    }
    // v: transpose in LDS
    {
        uint4 u0 = *(const uint4*)(qkv + rbase + 2048);
        uint4 u1 = *(const uint4*)(qkv + rbase + 2048 + 8);
        const unsigned* pu = (const unsigned*)&u0;
        #pragma unroll
        for (int j = 0; j < 4; ++j) {
            vt[(part * 16 + 2*j)     * 72 + row] = (unsigned short)(pu[j] & 0xffff);
            vt[(part * 16 + 2*j + 1) * 72 + row] = (unsigned short)(pu[j] >> 16);
        }
        pu = (const unsigned*)&u1;
        #pragma unroll
        for (int j = 0; j < 4; ++j) {
            vt[(part * 16 + 8 + 2*j)     * 72 + row] = (unsigned short)(pu[j] & 0xffff);
            vt[(part * 16 + 8 + 2*j + 1) * 72 + row] = (unsigned short)(pu[j] >> 16);
        }
    }
    __syncthreads();
    {
        int d = tid >> 2, seg = tid & 3;
        uint4 w0 = *(const uint4*)(vt + d * 72 + seg * 16);
        uint4 w1 = *(const uint4*)(vt + d * 72 + seg * 16 + 8);
        size_t vdst = (size_t)bh * 65536 + (size_t)d * 1024 + t0 + seg * 16;
        *(uint4*)(Vtg + vdst)     = w0;
        *(uint4*)(Vtg + vdst + 8) = w1;
    }
}

// ---------------- MFMA attention ----------------
__global__ __launch_bounds__(256)
void k_attn_mfma(const unsigned short* __restrict__ Qb,
                 const unsigned short* __restrict__ Kb,
                 const unsigned short* __restrict__ Vtg,
                 unsigned short* __restrict__ outp) {
    __shared__ unsigned short Kt[128 * 64];   // swizzled: 16B-granule col16 ^= (row&7)
    __shared__ unsigned short Vl[64 * 136];   // [d][k], stride 136
    int bh = blockIdx.x;
    int t0 = blockIdx.y * 64;
    int tid = threadIdx.x, wid = tid >> 6, lane = tid & 63;
    int li = lane & 15, lg = lane >> 4;
    const size_t bh64k = (size_t)bh * 65536;

    bf16x8 q0, q1;
    {
        const unsigned short* Qg = Qb + bh64k + (size_t)(t0 + wid * 16 + li) * 64 + lg * 8;
        q0 = *(const bf16x8*)Qg;
        q1 = *(const bf16x8*)(Qg + 32);
    }
    f32x4 oacc[4] = {};
    float den = 0.f;

    for (int kt = 0; kt < 8; ++kt) {
        __syncthreads();
        #pragma unroll
        for (int i = 0; i < 4; ++i) {
            int s = i * 256 + tid;
            int r = s >> 3, c16 = s & 7;
            const unsigned short* src = Kb + bh64k + (size_t)(kt * 128 + r) * 64 + ((c16 ^ (r & 7)) * 8);
            unsigned short* dst = Kt + i * 2048 + wid * 512;
            __builtin_amdgcn_global_load_lds((const __attribute__((address_space(1))) void*)src,
                                             (__attribute__((address_space(3))) void*)dst, 16, 0, 0);
        }
        #pragma unroll
        for (int i = 0; i < 4; ++i) {
            int s = i * 256 + tid;
            int d = s >> 4, k16 = s & 15;
            uint4 v = *(const uint4*)(Vtg + bh64k + (size_t)d * 1024 + kt * 128 + k16 * 8);
            *(uint4*)(Vl + d * 136 + k16 * 8) = v;
        }
        __syncthreads();

        f32x4 st[8];
        #pragma unroll
        for (int f = 0; f < 8; ++f) {
            int row = f * 16 + li;
            bf16x8 a0 = *(const bf16x8*)(Kt + row * 64 + ((lg       ^ (row & 7)) * 8));
            bf16x8 a1 = *(const bf16x8*)(Kt + row * 64 + (((4 + lg) ^ (row & 7)) * 8));
            f32x4 s = {};
            s = __builtin_amdgcn_mfma_f32_16x16x32_bf16(a0, q0, s, 0, 0, 0);
            s = __builtin_amdgcn_mfma_f32_16x16x32_bf16(a1, q1, s, 0, 0, 0);
            f32x4 e;
            e[0] = __expf(s[0]); e[1] = __expf(s[1]);
            e[2] = __expf(s[2]); e[3] = __expf(s[3]);
            den += e[0] + e[1] + e[2] + e[3];
            st[f] = e;
        }
        #pragma unroll
        for (int ks = 0; ks < 4; ++ks) {
            f32x4 e0 = st[2 * ks], e1 = st[2 * ks + 1];
            bf16x8 pa;
            pa[0] = (__bf16)e0[0]; pa[1] = (__bf16)e0[1]; pa[2] = (__bf16)e0[2]; pa[3] = (__bf16)e0[3];
            pa[4] = (__bf16)e1[0]; pa[5] = (__bf16)e1[1]; pa[6] = (__bf16)e1[2]; pa[7] = (__bf16)e1[3];
            #pragma unroll
            for (int df = 0; df < 4; ++df) {
                const unsigned short* vp = Vl + (df * 16 + li) * 136 + ks * 32 + lg * 4;
                bf16x4 v0 = *(const bf16x4*)vp;
                bf16x4 v1 = *(const bf16x4*)(vp + 16);
                bf16x8 vb = __builtin_shufflevector(v0, v1, 0, 1, 2, 3, 4, 5, 6, 7);
                oacc[df] = __builtin_amdgcn_mfma_f32_16x16x32_bf16(pa, vb, oacc[df], 0, 0, 0);
            }
        }
    }
    den += __shfl_xor(den, 16);
    den += __shfl_xor(den, 32);

    int b = bh >> 4, h = bh & 15;
    #pragma unroll
    for (int r2 = 0; r2 < 4; ++r2) {
        float dm = __shfl(den, lg * 4 + r2);
        float inv = 1.f / dm;
        int t = t0 + wid * 16 + lg * 4 + r2;
        #pragma unroll
        for (int df = 0; df < 4; ++df) {
            int col = h * 64 + df * 16 + li;
            outp[((size_t)(b * 1024 + t)) * 1024 + col] = f2bf(oacc[df][r2] * inv);
        }
    }
}

extern "C" void kernel_launch(void* const* d_in, const int* in_sizes, int n_in,
                              void* d_out, int out_size, void* d_ws, size_t ws_size,
                              hipStream_t stream) {
    const float* x     = (const float*)d_in[0];
    const float* c     = (const float*)d_in[1];
    const float* g1    = (const float*)d_in[2];
    const float* g2    = (const float*)d_in[3];
    const float* gq    = (const float*)d_in[4];
    const float* gk    = (const float*)d_in[5];
    const float* Wqkv  = (const float*)d_in[6];
    const float* bqkv  = (const float*)d_in[7];
    const float* Wproj = (const float*)d_in[8];
    const float* bproj = (const float*)d_in[9];
    const float* Wfc1  = (const float*)d_in[10];
    const float* bfc1  = (const float*)d_in[11];
    const float* Wfc2  = (const float*)d_in[12];
    const float* bfc2  = (const float*)d_in[13];
    const float* Wada  = (const float*)d_in[14];
    const float* bada  = (const float*)d_in[15];
    float* out = (float*)d_out;

    char* ws = (char*)d_ws;
    unsigned short* wqkv_bf = (unsigned short*)ws; ws += (size_t)3072 * 1024 * 2;
    unsigned short* wproj_bf= (unsigned short*)ws; ws += (size_t)1024 * 1024 * 2;
    unsigned short* wfc1_bf = (unsigned short*)ws; ws += (size_t)4096 * 1024 * 2;
    unsigned short* wfc2_bf = (unsigned short*)ws; ws += (size_t)4096 * 1024 * 2;
    float* ada = (float*)ws;                       ws += (size_t)8 * 6144 * 4;
    unsigned short* hbuf = (unsigned short*)ws;    ws += (size_t)8192 * 1024 * 2;   // h / o / h2
    unsigned short* qkvb16 = (unsigned short*)ws;  ws += (size_t)8192 * 3072 * 2;   // bf16 qkv
    unsigned short* Qb  = (unsigned short*)ws;     ws += (size_t)8192 * 64 * 16 * 2;
    unsigned short* Kb  = (unsigned short*)ws;     ws += (size_t)8192 * 64 * 16 * 2;
    unsigned short* Vtg = (unsigned short*)ws;     ws += (size_t)8192 * 64 * 16 * 2;
    unsigned short* fc1out = qkvb16;               // reuse (qkv dead by fc1)

    // 1) weight converts
    k_cvt<<<3072 * 1024 / 1024, 256, 0, stream>>>(Wqkv,  wqkv_bf);
    k_cvt<<<1024 * 1024 / 1024, 256, 0, stream>>>(Wproj, wproj_bf);
    k_cvt<<<4096 * 1024 / 1024, 256, 0, stream>>>(Wfc1,  wfc1_bf);
    k_cvt<<<4096 * 1024 / 1024, 256, 0, stream>>>(Wfc2,  wfc2_bf);
    // 2) adaLN
    k_ada<<<dim3(8, 1536), 256, 0, stream>>>(c, Wada, bada, ada);
    // 3) h = modulate(rmsnorm(x), scale_msa, shift_msa)
    k_norm_mod<<<8192, 256, 0, stream>>>(x, ada, g1, hbuf, 0, 1024);
    // 4) qkv = h @ Wqkv^T + bqkv (bf16)   grid 32x12 = 384
    k_gemm2<0, 256><<<384, 512, 0, stream>>>(hbuf, wqkv_bf, bqkv, 3072, 1024, 32,
                                             nullptr, qkvb16, nullptr, nullptr, 0);
    // 5) q/k norm + V transpose
    k_qkv_post<<<dim3(128, 16), 256, 0, stream>>>(qkvb16, gq, gk, Qb, Kb, Vtg);
    // 6) MFMA attention -> o (bf16, reuse hbuf)
    k_attn_mfma<<<dim3(128, 16), 256, 0, stream>>>(Qb, Kb, Vtg, hbuf);
    // 7) x1 = x + gate_msa * (o @ Wproj^T + bproj) -> d_out   grid 32x8 = 256
    k_gemm2<1, 128><<<256, 512, 0, stream>>>(hbuf, wproj_bf, bproj, 1024, 1024, 32,
                                             out, nullptr, x, ada, 2048);
    // 8) h2 = modulate(rmsnorm(x1), scale_mlp, shift_mlp)
    k_norm_mod<<<8192, 256, 0, stream>>>(out, ada, g2, hbuf, 3072, 4096);
    // 9) fc1 + gelu -> bf16   grid 32x16 = 512
    k_gemm2<2, 256><<<512, 512, 0, stream>>>(hbuf, wfc1_bf, bfc1, 4096, 1024, 32,
                                             nullptr, fc1out, nullptr, nullptr, 0);
    // 10) out = x1 + gate_mlp * (fc1out @ Wfc2^T + bfc2)   grid 32x8 = 256
    k_gemm2<3, 128><<<256, 512, 0, stream>>>(fc1out, wfc2_bf, bfc2, 1024, 4096, 32,
                                             out, nullptr, out, ada, 5120);
}

// Round 4
// 477.703 us; speedup vs baseline: 1.0370x; 1.0370x over previous
//
#include <hip/hip_runtime.h>
#include <hip/hip_bf16.h>
#include <math.h>

typedef __bf16 bf16x8 __attribute__((ext_vector_type(8)));
typedef __bf16 bf16x4 __attribute__((ext_vector_type(4)));
typedef float  f32x4  __attribute__((ext_vector_type(4)));

#define DEV static __device__ __forceinline__

DEV unsigned short f2bf(float f) {
    unsigned u = __builtin_bit_cast(unsigned, f);
    u += 0x7fffu + ((u >> 16) & 1u);     // RNE
    return (unsigned short)(u >> 16);
}
DEV float bf2f(unsigned short u) {
    unsigned x = ((unsigned)u) << 16;
    return __builtin_bit_cast(float, x);
}

// ---------------- fp32 -> bf16 weight convert ----------------
__global__ void k_cvt(const float* __restrict__ in, unsigned short* __restrict__ out) {
    int i = (blockIdx.x * 256 + threadIdx.x) * 4;
    float4 v = *(const float4*)(in + i);
    ushort4 o;
    o.x = f2bf(v.x); o.y = f2bf(v.y); o.z = f2bf(v.z); o.w = f2bf(v.w);
    *(ushort4*)(out + i) = o;
}

// ---------------- adaLN: ada = silu(c) @ Wada^T + bada ----------------
__global__ void k_ada(const float* __restrict__ c, const float* __restrict__ Wada,
                      const float* __restrict__ bada, float* __restrict__ ada) {
    __shared__ float sc[1024];
    int b = blockIdx.x;
    int tid = threadIdx.x;
    for (int k = tid; k < 1024; k += 256) {
        float x = c[b * 1024 + k];
        sc[k] = x / (1.f + __expf(-x));
    }
    __syncthreads();
    int wid = tid >> 6, lane = tid & 63;
    int n = blockIdx.y * 4 + wid;
    const float* wr = Wada + (size_t)n * 1024;
    float acc = 0.f;
    #pragma unroll
    for (int k = 0; k < 1024; k += 64) acc += sc[k + lane] * wr[k + lane];
    #pragma unroll
    for (int o = 32; o; o >>= 1) acc += __shfl_xor(acc, o);
    if (lane == 0) ada[b * 6144 + n] = acc + bada[n];
}

// ---------------- fused rmsnorm + modulate -> bf16 ----------------
__global__ void k_norm_mod(const float* __restrict__ x, const float* __restrict__ ada,
                           const float* __restrict__ g, unsigned short* __restrict__ h,
                           int shift_off, int scale_off) {
    int row = blockIdx.x;
    int b = row >> 10;
    int tid = threadIdx.x;
    float4 v = *(const float4*)(x + (size_t)row * 1024 + tid * 4);
    float ss = v.x * v.x + v.y * v.y + v.z * v.z + v.w * v.w;
    #pragma unroll
    for (int o = 32; o; o >>= 1) ss += __shfl_xor(ss, o);
    __shared__ float red[4];
    int wid = tid >> 6, lane = tid & 63;
    if (lane == 0) red[wid] = ss;
    __syncthreads();
    float nrm = sqrtf(red[0] + red[1] + red[2] + red[3]);
    float f = g[0] * 32.f / fmaxf(nrm, 1e-12f);
    float4 s4 = *(const float4*)(ada + b * 6144 + scale_off + tid * 4);
    float4 h4 = *(const float4*)(ada + b * 6144 + shift_off + tid * 4);
    ushort4 o;
    o.x = f2bf(v.x * f * (1.f + s4.x) + h4.x);
    o.y = f2bf(v.y * f * (1.f + s4.y) + h4.y);
    o.z = f2bf(v.z * f * (1.f + s4.z) + h4.z);
    o.w = f2bf(v.w * f * (1.f + s4.w) + h4.w);
    *(ushort4*)(h + (size_t)row * 1024 + tid * 4) = o;
}

// ============ pipelined bf16 GEMM: C[m,n] = sum_k A[m,k]*B[n,k] (+epilogue) ============
// BM=256, BN=256/128, BK=32, 512 threads (8 waves), 4-slot LDS ring, stage depth 3,
// counted vmcnt (never 0 in steady state), XOR-swizzled LDS, setprio MFMA clusters.
// Block mapping: mb = bid % gridM (gridM % 8 == 0) -> with round-robin XCD dispatch
// (XCD = bid % 8), each XCD owns the A-row shard mb%8==x, which stays L2-resident
// across all n-passes (round-2's measured 57MB FETCH property). No XCD chunk swizzle.
// EPI: 0 = +bias -> bf16 | 1 = resid+gate*(+bias) -> f32 | 2 = gelu(+bias) -> bf16
//      3 = resid+gate*(+bias) -> f32
template <int EPI, int BN>
__global__ __launch_bounds__(512, 2)
void k_gemm2(const unsigned short* __restrict__ A, const unsigned short* __restrict__ Bw,
             const float* __restrict__ bias, int N, int K, int gridM,
             float* __restrict__ outF, unsigned short* __restrict__ outH,
             const float* __restrict__ resid, const float* __restrict__ ada, int gate_off) {
    constexpr int WN = (BN == 256) ? 4 : 2;     // waves along N
    constexpr int WM = 8 / WN;                  // waves along M
    constexpr int WR = 256 / WM;                // rows per wave (128 / 64)
    constexpr int MF = WR / 16;                 // m-frags per wave (8 / 4)
    constexpr int MF2 = MF / 2;
    constexpr int LB = BN / 128;                // B loads/thread/tile (2 / 1)
    constexpr int TL = 2 + LB;                  // loads/wave/tile
    __shared__ unsigned short sA[4][256 * 32];
    __shared__ unsigned short sB[4][BN * 32];

    int tid = threadIdx.x;
    int wid = tid >> 6, lane = tid & 63;
    int li = lane & 15, lg = lane >> 4;

    // natural mapping: A-row shard per XCD (mb % 8 == bid % 8 == XCD)
    int bid = blockIdx.x;
    int mb = bid % gridM, nb = bid / gridM;
    int m0 = mb * 256, n0 = nb * BN;

    int wr = (wid / WN) * WR, wc = (wid % WN) * 64;

    // stage-side swizzle: granule g of row r sources global granule g ^ f(r)
    int arow = tid >> 2, ag = tid & 3;
    int afr = (arow & 3) ^ ((arow >> 2) & 3);
    int ags = (ag ^ afr) * 8;                   // element offset within 32-elem K slice
    // read-side: row & 15 == li for all fragment rows
    int lfr = (li & 3) ^ ((li >> 2) & 3);
    int aoff = li * 32 + ((lg ^ lfr) * 8);      // element offset within a tile row block

    auto stageA = [&](int t) {
        int slot = t & 3;
        int kk = t << 5;
        #pragma unroll
        for (int l = 0; l < 2; ++l) {
            int row = arow + l * 128;
            const unsigned short* src = A + (size_t)(m0 + row) * K + kk + ags;
            unsigned short* dst = &sA[slot][0] + (l * 512 + wid * 64) * 8;  // wave-uniform
            __builtin_amdgcn_global_load_lds((const __attribute__((address_space(1))) void*)src,
                                             (__attribute__((address_space(3))) void*)dst, 16, 0, 0);
        }
    };
    auto stageB = [&](int t) {
        int slot = t & 3;
        int kk = t << 5;
        #pragma unroll
        for (int l = 0; l < LB; ++l) {
            int row = arow + l * 128;
            const unsigned short* src = Bw + (size_t)(n0 + row) * K + kk + ags;
            unsigned short* dst = &sB[slot][0] + (l * 512 + wid * 64) * 8;
            __builtin_amdgcn_global_load_lds((const __attribute__((address_space(1))) void*)src,
                                             (__attribute__((address_space(3))) void*)dst, 16, 0, 0);
        }
    };

    int NT = K >> 5;
    // prologue: stage tiles 0,1,2; wait tile 0 landed (2 tiles may stay in flight)
    stageA(0); stageB(0); stageA(1); stageB(1); stageA(2); stageB(2);
    asm volatile("s_waitcnt vmcnt(%0)" :: "n"(2 * TL) : "memory");
    __builtin_amdgcn_s_barrier();

    f32x4 acc[MF][4] = {};

    for (int t = 0; t < NT; ++t) {
        int slot = t & 3;
        const unsigned short* pa = &sA[slot][0];
        const unsigned short* pb = &sB[slot][0];
        bf16x8 bfr[4];
        bf16x8 af[MF2];
        // ---- phase 0: stage A(t+3) | read B-frags + A-half 0 | MFMA ----
        if (t + 3 < NT) stageA(t + 3);
        #pragma unroll
        for (int nf = 0; nf < 4; ++nf)
            bfr[nf] = *(const bf16x8*)(pb + (wc + nf * 16) * 32 + aoff);
        #pragma unroll
        for (int m = 0; m < MF2; ++m)
            af[m] = *(const bf16x8*)(pa + (wr + m * 16) * 32 + aoff);
        __builtin_amdgcn_s_barrier();
        __builtin_amdgcn_s_setprio(1);
        #pragma unroll
        for (int m = 0; m < MF2; ++m)
            #pragma unroll
            for (int nf = 0; nf < 4; ++nf)
                acc[m][nf] = __builtin_amdgcn_mfma_f32_16x16x32_bf16(af[m], bfr[nf], acc[m][nf], 0, 0, 0);
        __builtin_amdgcn_s_setprio(0);
        // ---- phase 1: stage B(t+3) | read A-half 1 | MFMA ----
        if (t + 3 < NT) stageB(t + 3);
        #pragma unroll
        for (int m = 0; m < MF2; ++m)
            af[m] = *(const bf16x8*)(pa + (wr + (MF2 + m) * 16) * 32 + aoff);
        __builtin_amdgcn_s_barrier();
        __builtin_amdgcn_s_setprio(1);
        #pragma unroll
        for (int m = 0; m < MF2; ++m)
            #pragma unroll
            for (int nf = 0; nf < 4; ++nf)
                acc[MF2 + m][nf] = __builtin_amdgcn_mfma_f32_16x16x32_bf16(af[m], bfr[nf], acc[MF2 + m][nf], 0, 0, 0);
        __builtin_amdgcn_s_setprio(0);
        // ---- tile end: counted vmcnt so tile t+1 is landed; never 0 until tail ----
        if (t < NT - 3)       asm volatile("s_waitcnt vmcnt(%0)" :: "n"(2 * TL) : "memory");
        else if (t == NT - 3) asm volatile("s_waitcnt vmcnt(%0)" :: "n"(TL) : "memory");
        else if (t == NT - 2) asm volatile("s_waitcnt vmcnt(0)" ::: "memory");
        __builtin_amdgcn_s_barrier();
    }

    // epilogue
    int rb4 = lg * 4;
    #pragma unroll
    for (int mf = 0; mf < MF; ++mf) {
        #pragma unroll
        for (int nf = 0; nf < 4; ++nf) {
            #pragma unroll
            for (int r = 0; r < 4; ++r) {
                int row = m0 + wr + mf * 16 + rb4 + r;
                int col = n0 + wc + nf * 16 + li;
                float vv = acc[mf][nf][r] + bias[col];
                if (EPI == 0) {
                    outH[(size_t)row * N + col] = f2bf(vv);
                } else if (EPI == 2) {
                    float a2 = 0.7978845608f * (vv + 0.044715f * vv * vv * vv);
                    float e = __expf(-2.f * fabsf(a2));
                    float th = copysignf((1.f - e) / (1.f + e), a2);
                    outH[(size_t)row * N + col] = f2bf(0.5f * vv * (1.f + th));
                } else {
                    int b = row >> 10;
                    float gt = ada[b * 6144 + gate_off + col];
                    outF[(size_t)row * N + col] = resid[(size_t)row * N + col] + gt * vv;
                }
            }
        }
    }
}

// ---------------- qkv post: q/k rms-norm -> Qb/Kb bf16; V -> Vt [B,H,64,T] ----------------
__global__ __launch_bounds__(256)
void k_qkv_post(const unsigned short* __restrict__ qkv,   // [8192][3072] bf16
                const float* __restrict__ gq, const float* __restrict__ gk,
                unsigned short* __restrict__ Qb, unsigned short* __restrict__ Kb,
                unsigned short* __restrict__ Vtg) {
    __shared__ unsigned short vt[64 * 72];
    int bh = blockIdx.x;
    int b = bh >> 4, h = bh & 15;
    int t0 = blockIdx.y * 64;
    int tid = threadIdx.x;
    int row = tid >> 2, part = tid & 3;
    size_t rbase = ((size_t)(b * 1024 + t0 + row)) * 3072 + h * 64 + part * 16;
    size_t obase = (size_t)bh * 65536 + (size_t)(t0 + row) * 64 + part * 16;

    #pragma unroll
    for (int s = 0; s < 2; ++s) {   // 0 = q, 1 = k
        uint4 u0 = *(const uint4*)(qkv + rbase + s * 1024);
        uint4 u1 = *(const uint4*)(qkv + rbase + s * 1024 + 8);
        float vals[16];
        const unsigned* pu = (const unsigned*)&u0;
        #pragma unroll
        for (int j = 0; j < 4; ++j) {
            vals[2*j]   = bf2f((unsigned short)(pu[j] & 0xffff));
            vals[2*j+1] = bf2f((unsigned short)(pu[j] >> 16));
        }
        pu = (const unsigned*)&u1;
        #pragma unroll
        for (int j = 0; j < 4; ++j) {
            vals[8+2*j]   = bf2f((unsigned short)(pu[j] & 0xffff));
            vals[8+2*j+1] = bf2f((unsigned short)(pu[j] >> 16));
        }
        float ss = 0.f;
        #pragma unroll
        for (int j = 0; j < 16; ++j) ss += vals[j] * vals[j];
        ss += __shfl_xor(ss, 1);
        ss += __shfl_xor(ss, 2);
        float nrm = fmaxf(sqrtf(ss), 1e-12f);
        float fsc = (s == 0 ? gq[0] : 8.f * gk[0]) / nrm;
        uint4 w0, w1;
        unsigned* pw = (unsigned*)&w0;
        #pragma unroll
        for (int j = 0; j < 4; ++j)
            pw[j] = (unsigned)f2bf(vals[2*j] * fsc) | ((unsigned)f2bf(vals[2*j+1] * fsc) << 16);
        pw = (unsigned*)&w1;
        #pragma unroll
        for (int j = 0; j < 4; ++j)
            pw[j] = (unsigned)f2bf(vals[8+2*j] * fsc) | ((unsigned)f2bf(vals[8+2*j+1] * fsc) << 16);
        unsigned short* dst = (s == 0 ? Qb : Kb);
        *(uint4*)(dst + obase)     = w0;
        *(uint4*)(dst + obase + 8) = w1;
    }
    // v: transpose in LDS
    {
        uint4 u0 = *(const uint4*)(qkv + rbase + 2048);
        uint4 u1 = *(const uint4*)(qkv + rbase + 2048 + 8);
        const unsigned* pu = (const unsigned*)&u0;
        #pragma unroll
        for (int j = 0; j < 4; ++j) {
            vt[(part * 16 + 2*j)     * 72 + row] = (unsigned short)(pu[j] & 0xffff);
            vt[(part * 16 + 2*j + 1) * 72 + row] = (unsigned short)(pu[j] >> 16);
        }
        pu = (const unsigned*)&u1;
        #pragma unroll
        for (int j = 0; j < 4; ++j) {
            vt[(part * 16 + 8 + 2*j)     * 72 + row] = (unsigned short)(pu[j] & 0xffff);
            vt[(part * 16 + 8 + 2*j + 1) * 72 + row] = (unsigned short)(pu[j] >> 16);
        }
    }
    __syncthreads();
    {
        int d = tid >> 2, seg = tid & 3;
        uint4 w0 = *(const uint4*)(vt + d * 72 + seg * 16);
        uint4 w1 = *(const uint4*)(vt + d * 72 + seg * 16 + 8);
        size_t vdst = (size_t)bh * 65536 + (size_t)d * 1024 + t0 + seg * 16;
        *(uint4*)(Vtg + vdst)     = w0;
        *(uint4*)(Vtg + vdst + 8) = w1;
    }
}

// ---------------- MFMA attention ----------------
__global__ __launch_bounds__(256)
void k_attn_mfma(const unsigned short* __restrict__ Qb,
                 const unsigned short* __restrict__ Kb,
                 const unsigned short* __restrict__ Vtg,
                 unsigned short* __restrict__ outp) {
    __shared__ unsigned short Kt[128 * 64];   // swizzled: 16B-granule col16 ^= (row&7)
    __shared__ unsigned short Vl[64 * 136];   // [d][k], stride 136
    int bh = blockIdx.x;
    int t0 = blockIdx.y * 64;
    int tid = threadIdx.x, wid = tid >> 6, lane = tid & 63;
    int li = lane & 15, lg = lane >> 4;
    const size_t bh64k = (size_t)bh * 65536;

    bf16x8 q0, q1;
    {
        const unsigned short* Qg = Qb + bh64k + (size_t)(t0 + wid * 16 + li) * 64 + lg * 8;
        q0 = *(const bf16x8*)Qg;
        q1 = *(const bf16x8*)(Qg + 32);
    }
    f32x4 oacc[4] = {};
    float den = 0.f;

    for (int kt = 0; kt < 8; ++kt) {
        __syncthreads();
        #pragma unroll
        for (int i = 0; i < 4; ++i) {
            int s = i * 256 + tid;
            int r = s >> 3, c16 = s & 7;
            const unsigned short* src = Kb + bh64k + (size_t)(kt * 128 + r) * 64 + ((c16 ^ (r & 7)) * 8);
            unsigned short* dst = Kt + i * 2048 + wid * 512;
            __builtin_amdgcn_global_load_lds((const __attribute__((address_space(1))) void*)src,
                                             (__attribute__((address_space(3))) void*)dst, 16, 0, 0);
        }
        #pragma unroll
        for (int i = 0; i < 4; ++i) {
            int s = i * 256 + tid;
            int d = s >> 4, k16 = s & 15;
            uint4 v = *(const uint4*)(Vtg + bh64k + (size_t)d * 1024 + kt * 128 + k16 * 8);
            *(uint4*)(Vl + d * 136 + k16 * 8) = v;
        }
        __syncthreads();

        f32x4 st[8];
        #pragma unroll
        for (int f = 0; f < 8; ++f) {
            int row = f * 16 + li;
            bf16x8 a0 = *(const bf16x8*)(Kt + row * 64 + ((lg       ^ (row & 7)) * 8));
            bf16x8 a1 = *(const bf16x8*)(Kt + row * 64 + (((4 + lg) ^ (row & 7)) * 8));
            f32x4 s = {};
            s = __builtin_amdgcn_mfma_f32_16x16x32_bf16(a0, q0, s, 0, 0, 0);
            s = __builtin_amdgcn_mfma_f32_16x16x32_bf16(a1, q1, s, 0, 0, 0);
            f32x4 e;
            e[0] = __expf(s[0]); e[1] = __expf(s[1]);
            e[2] = __expf(s[2]); e[3] = __expf(s[3]);
            den += e[0] + e[1] + e[2] + e[3];
            st[f] = e;
        }
        #pragma unroll
        for (int ks = 0; ks < 4; ++ks) {
            f32x4 e0 = st[2 * ks], e1 = st[2 * ks + 1];
            bf16x8 pa;
            pa[0] = (__bf16)e0[0]; pa[1] = (__bf16)e0[1]; pa[2] = (__bf16)e0[2]; pa[3] = (__bf16)e0[3];
            pa[4] = (__bf16)e1[0]; pa[5] = (__bf16)e1[1]; pa[6] = (__bf16)e1[2]; pa[7] = (__bf16)e1[3];
            #pragma unroll
            for (int df = 0; df < 4; ++df) {
                const unsigned short* vp = Vl + (df * 16 + li) * 136 + ks * 32 + lg * 4;
                bf16x4 v0 = *(const bf16x4*)vp;
                bf16x4 v1 = *(const bf16x4*)(vp + 16);
                bf16x8 vb = __builtin_shufflevector(v0, v1, 0, 1, 2, 3, 4, 5, 6, 7);
                oacc[df] = __builtin_amdgcn_mfma_f32_16x16x32_bf16(pa, vb, oacc[df], 0, 0, 0);
            }
        }
    }
    den += __shfl_xor(den, 16);
    den += __shfl_xor(den, 32);

    int b = bh >> 4, h = bh & 15;
    #pragma unroll
    for (int r2 = 0; r2 < 4; ++r2) {
        float dm = __shfl(den, lg * 4 + r2);
        float inv = 1.f / dm;
        int t = t0 + wid * 16 + lg * 4 + r2;
        #pragma unroll
        for (int df = 0; df < 4; ++df) {
            int col = h * 64 + df * 16 + li;
            outp[((size_t)(b * 1024 + t)) * 1024 + col] = f2bf(oacc[df][r2] * inv);
        }
    }
}

extern "C" void kernel_launch(void* const* d_in, const int* in_sizes, int n_in,
                              void* d_out, int out_size, void* d_ws, size_t ws_size,
                              hipStream_t stream) {
    const float* x     = (const float*)d_in[0];
    const float* c     = (const float*)d_in[1];
    const float* g1    = (const float*)d_in[2];
    const float* g2    = (const float*)d_in[3];
    const float* gq    = (const float*)d_in[4];
    const float* gk    = (const float*)d_in[5];
    const float* Wqkv  = (const float*)d_in[6];
    const float* bqkv  = (const float*)d_in[7];
    const float* Wproj = (const float*)d_in[8];
    const float* bproj = (const float*)d_in[9];
    const float* Wfc1  = (const float*)d_in[10];
    const float* bfc1  = (const float*)d_in[11];
    const float* Wfc2  = (const float*)d_in[12];
    const float* bfc2  = (const float*)d_in[13];
    const float* Wada  = (const float*)d_in[14];
    const float* bada  = (const float*)d_in[15];
    float* out = (float*)d_out;

    char* ws = (char*)d_ws;
    unsigned short* wqkv_bf = (unsigned short*)ws; ws += (size_t)3072 * 1024 * 2;
    unsigned short* wproj_bf= (unsigned short*)ws; ws += (size_t)1024 * 1024 * 2;
    unsigned short* wfc1_bf = (unsigned short*)ws; ws += (size_t)4096 * 1024 * 2;
    unsigned short* wfc2_bf = (unsigned short*)ws; ws += (size_t)4096 * 1024 * 2;
    float* ada = (float*)ws;                       ws += (size_t)8 * 6144 * 4;
    unsigned short* hbuf = (unsigned short*)ws;    ws += (size_t)8192 * 1024 * 2;   // h / o / h2
    unsigned short* qkvb16 = (unsigned short*)ws;  ws += (size_t)8192 * 3072 * 2;   // bf16 qkv
    unsigned short* Qb  = (unsigned short*)ws;     ws += (size_t)8192 * 64 * 16 * 2;
    unsigned short* Kb  = (unsigned short*)ws;     ws += (size_t)8192 * 64 * 16 * 2;
    unsigned short* Vtg = (unsigned short*)ws;     ws += (size_t)8192 * 64 * 16 * 2;
    unsigned short* fc1out = qkvb16;               // reuse (qkv dead by fc1)

    // 1) weight converts
    k_cvt<<<3072 * 1024 / 1024, 256, 0, stream>>>(Wqkv,  wqkv_bf);
    k_cvt<<<1024 * 1024 / 1024, 256, 0, stream>>>(Wproj, wproj_bf);
    k_cvt<<<4096 * 1024 / 1024, 256, 0, stream>>>(Wfc1,  wfc1_bf);
    k_cvt<<<4096 * 1024 / 1024, 256, 0, stream>>>(Wfc2,  wfc2_bf);
    // 2) adaLN
    k_ada<<<dim3(8, 1536), 256, 0, stream>>>(c, Wada, bada, ada);
    // 3) h = modulate(rmsnorm(x), scale_msa, shift_msa)
    k_norm_mod<<<8192, 256, 0, stream>>>(x, ada, g1, hbuf, 0, 1024);
    // 4) qkv = h @ Wqkv^T + bqkv (bf16)   grid 32x12 = 384
    k_gemm2<0, 256><<<384, 512, 0, stream>>>(hbuf, wqkv_bf, bqkv, 3072, 1024, 32,
                                             nullptr, qkvb16, nullptr, nullptr, 0);
    // 5) q/k norm + V transpose
    k_qkv_post<<<dim3(128, 16), 256, 0, stream>>>(qkvb16, gq, gk, Qb, Kb, Vtg);
    // 6) MFMA attention -> o (bf16, reuse hbuf)
    k_attn_mfma<<<dim3(128, 16), 256, 0, stream>>>(Qb, Kb, Vtg, hbuf);
    // 7) x1 = x + gate_msa * (o @ Wproj^T + bproj) -> d_out   grid 32x8 = 256
    k_gemm2<1, 128><<<256, 512, 0, stream>>>(hbuf, wproj_bf, bproj, 1024, 1024, 32,
                                             out, nullptr, x, ada, 2048);
    // 8) h2 = modulate(rmsnorm(x1), scale_mlp, shift_mlp)
    k_norm_mod<<<8192, 256, 0, stream>>>(out, ada, g2, hbuf, 3072, 4096);
    // 9) fc1 + gelu -> bf16   grid 32x16 = 512
    k_gemm2<2, 256><<<512, 512, 0, stream>>>(hbuf, wfc1_bf, bfc1, 4096, 1024, 32,
                                             nullptr, fc1out, nullptr, nullptr, 0);
    // 10) out = x1 + gate_mlp * (fc1out @ Wfc2^T + bfc2)   grid 32x8 = 256
    k_gemm2<3, 128><<<256, 512, 0, stream>>>(fc1out, wfc2_bf, bfc2, 1024, 4096, 32,
                                             out, nullptr, out, ada, 5120);
}

// Round 5
// 430.401 us; speedup vs baseline: 1.1509x; 1.1099x over previous
//
#include <hip/hip_runtime.h>
#include <hip/hip_bf16.h>
#include <math.h>

typedef __bf16 bf16x8 __attribute__((ext_vector_type(8)));
typedef __bf16 bf16x4 __attribute__((ext_vector_type(4)));
typedef float  f32x4  __attribute__((ext_vector_type(4)));

#define DEV static __device__ __forceinline__

DEV unsigned short f2bf(float f) {
    unsigned u = __builtin_bit_cast(unsigned, f);
    u += 0x7fffu + ((u >> 16) & 1u);     // RNE
    return (unsigned short)(u >> 16);
}
DEV float bf2f(unsigned short u) {
    unsigned x = ((unsigned)u) << 16;
    return __builtin_bit_cast(float, x);
}

// ---------------- fp32 -> bf16 weight convert ----------------
__global__ void k_cvt(const float* __restrict__ in, unsigned short* __restrict__ out) {
    int i = (blockIdx.x * 256 + threadIdx.x) * 4;
    float4 v = *(const float4*)(in + i);
    ushort4 o;
    o.x = f2bf(v.x); o.y = f2bf(v.y); o.z = f2bf(v.z); o.w = f2bf(v.w);
    *(ushort4*)(out + i) = o;
}

// ---------------- adaLN: ada = silu(c) @ Wada^T + bada ----------------
__global__ void k_ada(const float* __restrict__ c, const float* __restrict__ Wada,
                      const float* __restrict__ bada, float* __restrict__ ada) {
    __shared__ float sc[1024];
    int b = blockIdx.x;
    int tid = threadIdx.x;
    for (int k = tid; k < 1024; k += 256) {
        float x = c[b * 1024 + k];
        sc[k] = x / (1.f + __expf(-x));
    }
    __syncthreads();
    int wid = tid >> 6, lane = tid & 63;
    int n = blockIdx.y * 4 + wid;
    const float* wr = Wada + (size_t)n * 1024;
    float acc = 0.f;
    #pragma unroll
    for (int k = 0; k < 1024; k += 64) acc += sc[k + lane] * wr[k + lane];
    #pragma unroll
    for (int o = 32; o; o >>= 1) acc += __shfl_xor(acc, o);
    if (lane == 0) ada[b * 6144 + n] = acc + bada[n];
}

// ---------------- fused rmsnorm + modulate -> bf16 ----------------
__global__ void k_norm_mod(const float* __restrict__ x, const float* __restrict__ ada,
                           const float* __restrict__ g, unsigned short* __restrict__ h,
                           int shift_off, int scale_off) {
    int row = blockIdx.x;
    int b = row >> 10;
    int tid = threadIdx.x;
    float4 v = *(const float4*)(x + (size_t)row * 1024 + tid * 4);
    float ss = v.x * v.x + v.y * v.y + v.z * v.z + v.w * v.w;
    #pragma unroll
    for (int o = 32; o; o >>= 1) ss += __shfl_xor(ss, o);
    __shared__ float red[4];
    int wid = tid >> 6, lane = tid & 63;
    if (lane == 0) red[wid] = ss;
    __syncthreads();
    float nrm = sqrtf(red[0] + red[1] + red[2] + red[3]);
    float f = g[0] * 32.f / fmaxf(nrm, 1e-12f);
    float4 s4 = *(const float4*)(ada + b * 6144 + scale_off + tid * 4);
    float4 h4 = *(const float4*)(ada + b * 6144 + shift_off + tid * 4);
    ushort4 o;
    o.x = f2bf(v.x * f * (1.f + s4.x) + h4.x);
    o.y = f2bf(v.y * f * (1.f + s4.y) + h4.y);
    o.z = f2bf(v.z * f * (1.f + s4.z) + h4.z);
    o.w = f2bf(v.w * f * (1.f + s4.w) + h4.w);
    *(ushort4*)(h + (size_t)row * 1024 + tid * 4) = o;
}

// ============ pipelined bf16 GEMM v3: C[m,n] = sum_k A[m,k]*B[n,k] (+epilogue) ============
// BM=256, BN=128, BK=64, 512 threads (8 waves, 2M x 4N -> 128x32 per wave).
// 3-buffer LDS ring (144KB): tile t+2 staged into the buffer freed at end of tile t
// -> race-free, stage-to-use distance = 1 full K-tile; steady-state vmcnt(6), never 0.
// LDS rows are 128B/8 granules; slot = g ^ (row&7) -> 2-way-max bank pattern on
// ds_read_b128 (LDS floor). Applied involutively on the global source (linear LDS dst).
// EPI: 0 = +bias -> bf16 | 1 = resid+gate*(+bias) -> f32 | 2 = gelu(+bias) -> bf16
//      3 = resid+gate*(+bias) -> f32
template <int EPI>
__global__ __launch_bounds__(512, 2)
void k_gemm3(const unsigned short* __restrict__ A, const unsigned short* __restrict__ Bw,
             const float* __restrict__ bias, int N, int K,
             float* __restrict__ outF, unsigned short* __restrict__ outH,
             const float* __restrict__ resid, const float* __restrict__ ada, int gate_off) {
    constexpr int ASZ = 2 * 128 * 64;    // 16K elems = 32KB per K-tile
    constexpr int BSZ = 128 * 64;        // 8K elems = 16KB
    __shared__ unsigned short sA[3][ASZ];
    __shared__ unsigned short sB[3][BSZ];

    int tid = threadIdx.x;
    int wid = tid >> 6, lane = tid & 63;
    int li = lane & 15, lg = lane >> 4;
    int bid = blockIdx.x;
    int mb = bid & 31, nb = bid >> 5;    // mb%8 == XCD -> A-row shard L2-resident
    int m0 = mb * 256, n0 = nb * 128;
    int wc = (wid & 3) * 32;

    int trow = tid >> 3;                                  // 0..63 (staging row)
    int gcol = ((tid & 7) ^ (trow & 7)) * 8;              // pre-swizzled global granule
    int sx = li & 7;
    int abase = (wid >> 2) * 8192 + li * 64;              // A elem base (half + lane row)
    int g0 = (lg ^ sx) * 8;                               // ks=0 granule slot
    int g1 = ((4 + lg) ^ sx) * 8;                         // ks=1

    auto stageA = [&](int t) {
        int buf = t % 3; int kk = t << 6;
        #pragma unroll
        for (int l = 0; l < 4; ++l) {
            const unsigned short* src = A + (size_t)(m0 + l * 64 + trow) * K + kk + gcol;
            unsigned short* dst = &sA[buf][0] + (l * 512 + wid * 64) * 8;   // wave-uniform
            __builtin_amdgcn_global_load_lds((const __attribute__((address_space(1))) void*)src,
                                             (__attribute__((address_space(3))) void*)dst, 16, 0, 0);
        }
    };
    auto stageB = [&](int t) {
        int buf = t % 3; int kk = t << 6;
        #pragma unroll
        for (int l = 0; l < 2; ++l) {
            const unsigned short* src = Bw + (size_t)(n0 + l * 64 + trow) * K + kk + gcol;
            unsigned short* dst = &sB[buf][0] + (l * 512 + wid * 64) * 8;
            __builtin_amdgcn_global_load_lds((const __attribute__((address_space(1))) void*)src,
                                             (__attribute__((address_space(3))) void*)dst, 16, 0, 0);
        }
    };

    int NT = K >> 6;
    stageA(0); stageB(0); stageA(1); stageB(1);
    asm volatile("s_waitcnt vmcnt(6)" ::: "memory");       // tile 0 landed; tile 1 in flight
    __builtin_amdgcn_s_barrier();

    f32x4 acc[8][2] = {};

    for (int t = 0; t < NT; ++t) {
        int buf = t % 3;
        const unsigned short* pa = &sA[buf][0];
        const unsigned short* pb = &sB[buf][0];
        bool pre = (t + 2 < NT);
        // ---- phase 1: read B (both halves of K) + A m-half 0 | stage A(t+2) | 16 MFMA ----
        bf16x8 bfr[2][2];
        #pragma unroll
        for (int nf = 0; nf < 2; ++nf) {
            int rb = (wc + nf * 16 + li) * 64;
            bfr[nf][0] = *(const bf16x8*)(pb + rb + g0);
            bfr[nf][1] = *(const bf16x8*)(pb + rb + g1);
        }
        bf16x8 afr[4][2];
        #pragma unroll
        for (int mf = 0; mf < 4; ++mf) {
            afr[mf][0] = *(const bf16x8*)(pa + abase + mf * 1024 + g0);
            afr[mf][1] = *(const bf16x8*)(pa + abase + mf * 1024 + g1);
        }
        if (pre) stageA(t + 2);
        __builtin_amdgcn_s_barrier();
        __builtin_amdgcn_s_setprio(1);
        #pragma unroll
        for (int mf = 0; mf < 4; ++mf)
            #pragma unroll
            for (int nf = 0; nf < 2; ++nf) {
                acc[mf][nf] = __builtin_amdgcn_mfma_f32_16x16x32_bf16(afr[mf][0], bfr[nf][0], acc[mf][nf], 0, 0, 0);
                acc[mf][nf] = __builtin_amdgcn_mfma_f32_16x16x32_bf16(afr[mf][1], bfr[nf][1], acc[mf][nf], 0, 0, 0);
            }
        __builtin_amdgcn_s_setprio(0);
        // ---- phase 2: read A m-half 1 | stage B(t+2) | 16 MFMA ----
        #pragma unroll
        for (int mf = 0; mf < 4; ++mf) {
            afr[mf][0] = *(const bf16x8*)(pa + abase + (4 + mf) * 1024 + g0);
            afr[mf][1] = *(const bf16x8*)(pa + abase + (4 + mf) * 1024 + g1);
        }
        if (pre) stageB(t + 2);
        __builtin_amdgcn_s_barrier();
        __builtin_amdgcn_s_setprio(1);
        #pragma unroll
        for (int mf = 0; mf < 4; ++mf)
            #pragma unroll
            for (int nf = 0; nf < 2; ++nf) {
                acc[4 + mf][nf] = __builtin_amdgcn_mfma_f32_16x16x32_bf16(afr[mf][0], bfr[nf][0], acc[4 + mf][nf], 0, 0, 0);
                acc[4 + mf][nf] = __builtin_amdgcn_mfma_f32_16x16x32_bf16(afr[mf][1], bfr[nf][1], acc[4 + mf][nf], 0, 0, 0);
            }
        __builtin_amdgcn_s_setprio(0);
        // ---- tile end: t+1 must be landed; keep t+2's 6 loads in flight ----
        if (t < NT - 2)       asm volatile("s_waitcnt vmcnt(6)" ::: "memory");
        else if (t == NT - 2) asm volatile("s_waitcnt vmcnt(0)" ::: "memory");
        __builtin_amdgcn_s_barrier();
    }

    // epilogue: C row = m0 + (wid>>2)*128 + mf*16 + lg*4 + r ; col = n0 + wc + nf*16 + li
    int wm = (wid >> 2) * 128;
    int rb4 = lg * 4;
    #pragma unroll
    for (int mf = 0; mf < 8; ++mf) {
        #pragma unroll
        for (int nf = 0; nf < 2; ++nf) {
            #pragma unroll
            for (int r = 0; r < 4; ++r) {
                int row = m0 + wm + mf * 16 + rb4 + r;
                int col = n0 + wc + nf * 16 + li;
                float vv = acc[mf][nf][r] + bias[col];
                if (EPI == 0) {
                    outH[(size_t)row * N + col] = f2bf(vv);
                } else if (EPI == 2) {
                    float a2 = 0.7978845608f * (vv + 0.044715f * vv * vv * vv);
                    float e = __expf(-2.f * fabsf(a2));
                    float th = copysignf((1.f - e) / (1.f + e), a2);
                    outH[(size_t)row * N + col] = f2bf(0.5f * vv * (1.f + th));
                } else {
                    int b = row >> 10;
                    float gt = ada[b * 6144 + gate_off + col];
                    outF[(size_t)row * N + col] = resid[(size_t)row * N + col] + gt * vv;
                }
            }
        }
    }
}

// ---------------- qkv post: q/k rms-norm -> Qb/Kb bf16; V -> Vt [B,H,64,T] ----------------
__global__ __launch_bounds__(256)
void k_qkv_post(const unsigned short* __restrict__ qkv,   // [8192][3072] bf16
                const float* __restrict__ gq, const float* __restrict__ gk,
                unsigned short* __restrict__ Qb, unsigned short* __restrict__ Kb,
                unsigned short* __restrict__ Vtg) {
    __shared__ unsigned short vt[64 * 72];
    int bh = blockIdx.x;
    int b = bh >> 4, h = bh & 15;
    int t0 = blockIdx.y * 64;
    int tid = threadIdx.x;
    int row = tid >> 2, part = tid & 3;
    size_t rbase = ((size_t)(b * 1024 + t0 + row)) * 3072 + h * 64 + part * 16;
    size_t obase = (size_t)bh * 65536 + (size_t)(t0 + row) * 64 + part * 16;

    #pragma unroll
    for (int s = 0; s < 2; ++s) {   // 0 = q, 1 = k
        uint4 u0 = *(const uint4*)(qkv + rbase + s * 1024);
        uint4 u1 = *(const uint4*)(qkv + rbase + s * 1024 + 8);
        float vals[16];
        const unsigned* pu = (const unsigned*)&u0;
        #pragma unroll
        for (int j = 0; j < 4; ++j) {
            vals[2*j]   = bf2f((unsigned short)(pu[j] & 0xffff));
            vals[2*j+1] = bf2f((unsigned short)(pu[j] >> 16));
        }
        pu = (const unsigned*)&u1;
        #pragma unroll
        for (int j = 0; j < 4; ++j) {
            vals[8+2*j]   = bf2f((unsigned short)(pu[j] & 0xffff));
            vals[8+2*j+1] = bf2f((unsigned short)(pu[j] >> 16));
        }
        float ss = 0.f;
        #pragma unroll
        for (int j = 0; j < 16; ++j) ss += vals[j] * vals[j];
        ss += __shfl_xor(ss, 1);
        ss += __shfl_xor(ss, 2);
        float nrm = fmaxf(sqrtf(ss), 1e-12f);
        float fsc = (s == 0 ? gq[0] : 8.f * gk[0]) / nrm;
        uint4 w0, w1;
        unsigned* pw = (unsigned*)&w0;
        #pragma unroll
        for (int j = 0; j < 4; ++j)
            pw[j] = (unsigned)f2bf(vals[2*j] * fsc) | ((unsigned)f2bf(vals[2*j+1] * fsc) << 16);
        pw = (unsigned*)&w1;
        #pragma unroll
        for (int j = 0; j < 4; ++j)
            pw[j] = (unsigned)f2bf(vals[8+2*j] * fsc) | ((unsigned)f2bf(vals[8+2*j+1] * fsc) << 16);
        unsigned short* dst = (s == 0 ? Qb : Kb);
        *(uint4*)(dst + obase)     = w0;
        *(uint4*)(dst + obase + 8) = w1;
    }
    // v: transpose in LDS
    {
        uint4 u0 = *(const uint4*)(qkv + rbase + 2048);
        uint4 u1 = *(const uint4*)(qkv + rbase + 2048 + 8);
        const unsigned* pu = (const unsigned*)&u0;
        #pragma unroll
        for (int j = 0; j < 4; ++j) {
            vt[(part * 16 + 2*j)     * 72 + row] = (unsigned short)(pu[j] & 0xffff);
            vt[(part * 16 + 2*j + 1) * 72 + row] = (unsigned short)(pu[j] >> 16);
        }
        pu = (const unsigned*)&u1;
        #pragma unroll
        for (int j = 0; j < 4; ++j) {
            vt[(part * 16 + 8 + 2*j)     * 72 + row] = (unsigned short)(pu[j] & 0xffff);
            vt[(part * 16 + 8 + 2*j + 1) * 72 + row] = (unsigned short)(pu[j] >> 16);
        }
    }
    __syncthreads();
    {
        int d = tid >> 2, seg = tid & 3;
        uint4 w0 = *(const uint4*)(vt + d * 72 + seg * 16);
        uint4 w1 = *(const uint4*)(vt + d * 72 + seg * 16 + 8);
        size_t vdst = (size_t)bh * 65536 + (size_t)d * 1024 + t0 + seg * 16;
        *(uint4*)(Vtg + vdst)     = w0;
        *(uint4*)(Vtg + vdst + 8) = w1;
    }
}

// ---------------- MFMA attention ----------------
__global__ __launch_bounds__(256)
void k_attn_mfma(const unsigned short* __restrict__ Qb,
                 const unsigned short* __restrict__ Kb,
                 const unsigned short* __restrict__ Vtg,
                 unsigned short* __restrict__ outp) {
    __shared__ unsigned short Kt[128 * 64];   // swizzled: 16B-granule col16 ^= (row&7)
    __shared__ unsigned short Vl[64 * 136];   // [d][k], stride 136
    int bh = blockIdx.x;
    int t0 = blockIdx.y * 64;
    int tid = threadIdx.x, wid = tid >> 6, lane = tid & 63;
    int li = lane & 15, lg = lane >> 4;
    const size_t bh64k = (size_t)bh * 65536;

    bf16x8 q0, q1;
    {
        const unsigned short* Qg = Qb + bh64k + (size_t)(t0 + wid * 16 + li) * 64 + lg * 8;
        q0 = *(const bf16x8*)Qg;
        q1 = *(const bf16x8*)(Qg + 32);
    }
    f32x4 oacc[4] = {};
    float den = 0.f;

    for (int kt = 0; kt < 8; ++kt) {
        __syncthreads();
        #pragma unroll
        for (int i = 0; i < 4; ++i) {
            int s = i * 256 + tid;
            int r = s >> 3, c16 = s & 7;
            const unsigned short* src = Kb + bh64k + (size_t)(kt * 128 + r) * 64 + ((c16 ^ (r & 7)) * 8);
            unsigned short* dst = Kt + i * 2048 + wid * 512;
            __builtin_amdgcn_global_load_lds((const __attribute__((address_space(1))) void*)src,
                                             (__attribute__((address_space(3))) void*)dst, 16, 0, 0);
        }
        #pragma unroll
        for (int i = 0; i < 4; ++i) {
            int s = i * 256 + tid;
            int d = s >> 4, k16 = s & 15;
            uint4 v = *(const uint4*)(Vtg + bh64k + (size_t)d * 1024 + kt * 128 + k16 * 8);
            *(uint4*)(Vl + d * 136 + k16 * 8) = v;
        }
        __syncthreads();

        f32x4 st[8];
        #pragma unroll
        for (int f = 0; f < 8; ++f) {
            int row = f * 16 + li;
            bf16x8 a0 = *(const bf16x8*)(Kt + row * 64 + ((lg       ^ (row & 7)) * 8));
            bf16x8 a1 = *(const bf16x8*)(Kt + row * 64 + (((4 + lg) ^ (row & 7)) * 8));
            f32x4 s = {};
            s = __builtin_amdgcn_mfma_f32_16x16x32_bf16(a0, q0, s, 0, 0, 0);
            s = __builtin_amdgcn_mfma_f32_16x16x32_bf16(a1, q1, s, 0, 0, 0);
            f32x4 e;
            e[0] = __expf(s[0]); e[1] = __expf(s[1]);
            e[2] = __expf(s[2]); e[3] = __expf(s[3]);
            den += e[0] + e[1] + e[2] + e[3];
            st[f] = e;
        }
        #pragma unroll
        for (int ks = 0; ks < 4; ++ks) {
            f32x4 e0 = st[2 * ks], e1 = st[2 * ks + 1];
            bf16x8 pa;
            pa[0] = (__bf16)e0[0]; pa[1] = (__bf16)e0[1]; pa[2] = (__bf16)e0[2]; pa[3] = (__bf16)e0[3];
            pa[4] = (__bf16)e1[0]; pa[5] = (__bf16)e1[1]; pa[6] = (__bf16)e1[2]; pa[7] = (__bf16)e1[3];
            #pragma unroll
            for (int df = 0; df < 4; ++df) {
                const unsigned short* vp = Vl + (df * 16 + li) * 136 + ks * 32 + lg * 4;
                bf16x4 v0 = *(const bf16x4*)vp;
                bf16x4 v1 = *(const bf16x4*)(vp + 16);
                bf16x8 vb = __builtin_shufflevector(v0, v1, 0, 1, 2, 3, 4, 5, 6, 7);
                oacc[df] = __builtin_amdgcn_mfma_f32_16x16x32_bf16(pa, vb, oacc[df], 0, 0, 0);
            }
        }
    }
    den += __shfl_xor(den, 16);
    den += __shfl_xor(den, 32);

    int b = bh >> 4, h = bh & 15;
    #pragma unroll
    for (int r2 = 0; r2 < 4; ++r2) {
        float dm = __shfl(den, lg * 4 + r2);
        float inv = 1.f / dm;
        int t = t0 + wid * 16 + lg * 4 + r2;
        #pragma unroll
        for (int df = 0; df < 4; ++df) {
            int col = h * 64 + df * 16 + li;
            outp[((size_t)(b * 1024 + t)) * 1024 + col] = f2bf(oacc[df][r2] * inv);
        }
    }
}

extern "C" void kernel_launch(void* const* d_in, const int* in_sizes, int n_in,
                              void* d_out, int out_size, void* d_ws, size_t ws_size,
                              hipStream_t stream) {
    const float* x     = (const float*)d_in[0];
    const float* c     = (const float*)d_in[1];
    const float* g1    = (const float*)d_in[2];
    const float* g2    = (const float*)d_in[3];
    const float* gq    = (const float*)d_in[4];
    const float* gk    = (const float*)d_in[5];
    const float* Wqkv  = (const float*)d_in[6];
    const float* bqkv  = (const float*)d_in[7];
    const float* Wproj = (const float*)d_in[8];
    const float* bproj = (const float*)d_in[9];
    const float* Wfc1  = (const float*)d_in[10];
    const float* bfc1  = (const float*)d_in[11];
    const float* Wfc2  = (const float*)d_in[12];
    const float* bfc2  = (const float*)d_in[13];
    const float* Wada  = (const float*)d_in[14];
    const float* bada  = (const float*)d_in[15];
    float* out = (float*)d_out;

    char* ws = (char*)d_ws;
    unsigned short* wqkv_bf = (unsigned short*)ws; ws += (size_t)3072 * 1024 * 2;
    unsigned short* wproj_bf= (unsigned short*)ws; ws += (size_t)1024 * 1024 * 2;
    unsigned short* wfc1_bf = (unsigned short*)ws; ws += (size_t)4096 * 1024 * 2;
    unsigned short* wfc2_bf = (unsigned short*)ws; ws += (size_t)4096 * 1024 * 2;
    float* ada = (float*)ws;                       ws += (size_t)8 * 6144 * 4;
    unsigned short* hbuf = (unsigned short*)ws;    ws += (size_t)8192 * 1024 * 2;   // h / o / h2
    unsigned short* qkvb16 = (unsigned short*)ws;  ws += (size_t)8192 * 3072 * 2;   // bf16 qkv
    unsigned short* Qb  = (unsigned short*)ws;     ws += (size_t)8192 * 64 * 16 * 2;
    unsigned short* Kb  = (unsigned short*)ws;     ws += (size_t)8192 * 64 * 16 * 2;
    unsigned short* Vtg = (unsigned short*)ws;     ws += (size_t)8192 * 64 * 16 * 2;
    unsigned short* fc1out = qkvb16;               // reuse (qkv dead by fc1)

    // 1) weight converts
    k_cvt<<<3072 * 1024 / 1024, 256, 0, stream>>>(Wqkv,  wqkv_bf);
    k_cvt<<<1024 * 1024 / 1024, 256, 0, stream>>>(Wproj, wproj_bf);
    k_cvt<<<4096 * 1024 / 1024, 256, 0, stream>>>(Wfc1,  wfc1_bf);
    k_cvt<<<4096 * 1024 / 1024, 256, 0, stream>>>(Wfc2,  wfc2_bf);
    // 2) adaLN
    k_ada<<<dim3(8, 1536), 256, 0, stream>>>(c, Wada, bada, ada);
    // 3) h = modulate(rmsnorm(x), scale_msa, shift_msa)
    k_norm_mod<<<8192, 256, 0, stream>>>(x, ada, g1, hbuf, 0, 1024);
    // 4) qkv = h @ Wqkv^T + bqkv (bf16)   grid 32 x 24 = 768
    k_gemm3<0><<<768, 512, 0, stream>>>(hbuf, wqkv_bf, bqkv, 3072, 1024,
                                        nullptr, qkvb16, nullptr, nullptr, 0);
    // 5) q/k norm + V transpose
    k_qkv_post<<<dim3(128, 16), 256, 0, stream>>>(qkvb16, gq, gk, Qb, Kb, Vtg);
    // 6) MFMA attention -> o (bf16, reuse hbuf)
    k_attn_mfma<<<dim3(128, 16), 256, 0, stream>>>(Qb, Kb, Vtg, hbuf);
    // 7) x1 = x + gate_msa * (o @ Wproj^T + bproj) -> d_out   grid 32 x 8 = 256
    k_gemm3<1><<<256, 512, 0, stream>>>(hbuf, wproj_bf, bproj, 1024, 1024,
                                        out, nullptr, x, ada, 2048);
    // 8) h2 = modulate(rmsnorm(x1), scale_mlp, shift_mlp)
    k_norm_mod<<<8192, 256, 0, stream>>>(out, ada, g2, hbuf, 3072, 4096);
    // 9) fc1 + gelu -> bf16   grid 32 x 32 = 1024
    k_gemm3<2><<<1024, 512, 0, stream>>>(hbuf, wfc1_bf, bfc1, 4096, 1024,
                                         nullptr, fc1out, nullptr, nullptr, 0);
    // 10) out = x1 + gate_mlp * (fc1out @ Wfc2^T + bfc2)   grid 32 x 8 = 256
    k_gemm3<3><<<256, 512, 0, stream>>>(fc1out, wfc2_bf, bfc2, 1024, 4096,
                                        out, nullptr, out, ada, 5120);
}